// Round 11
// baseline (214.544 us; speedup 1.0000x reference)
//
#include <hip/hip_runtime.h>
#include <hip/hip_bf16.h>

// VectorQuantiser: x [32,64,64,64] f32, embeddings [64,1024] f32.
// argmin_k ||z - e_k||^2 over K=1024 for N=131072 rows of D=64; out = codewords.
//
//  k0 vq_prep:   ET[k][d] f32; ckseq[k] = sequential f32 sum e^2 (numpy order);
//                EB = bf16 HI-ONLY fragments of (-2e), lane-linear, 64 tiles
//                of 2048 B (+4 pad tiles) for per-wave register streaming.
//  k1 vq_mfma:   score = ck - 2*dot via 2-product MFMA (xh+xl)*eh, 4-deep
//                C-chain per row-tile. Barrier-free K-loop, per-wave B stream
//                from L2 with DISTANCE-4 rolling register prefetch (R10 pm:
//                distance-1 left ~100cyc/tile vmcnt stall; MfmaUtil 29%).
//                Score err sigma ~6.4e-4; MARGIN 8e-3 = 8.8 sigma.
//  k2 vq_refine2: wave per flagged row (~7k): exact numpy-f32 chain over all
//                1024 k (coalesced E[d][k] loads), packed-key argmin, direct
//                rewrite. Semantics validated R2-R10.

#define NROWS (32 * 64 * 64)   // 131072
#define DIM   64
#define KCB   1024
#define MARGIN 8e-3f

// ws layout (bytes):
#define ET_OFF    0           // float[1024*64] = 262144
#define CK_OFF    262144      // float[1088] pad -> 4352
#define EB_OFF    266496      // 68 tiles * 2048 B = 139264 (64 + 4 prefetch pad)
#define CNT_OFF   405760      // int (+pad)
#define LIST_OFF  406016      // int[cap]
#define LIST_CAP  12288

typedef float  f32x4 __attribute__((ext_vector_type(4)));
typedef short  s16x8 __attribute__((ext_vector_type(8)));

#define GLDS16(g, l) __builtin_amdgcn_global_load_lds( \
    (const __attribute__((address_space(1))) unsigned int*)(g), \
    (__attribute__((address_space(3))) unsigned int*)(l), 16, 0, 0)

static __device__ inline short bfb(float f) {   // f32 -> bf16 bits, RNE
    union { float f; unsigned u; } c{f};
    unsigned r = c.u + 0x7fffu + ((c.u >> 16) & 1u);
    return (short)(r >> 16);
}
static __device__ inline float bf2f(short b) {  // bf16 bits -> f32
    union { unsigned u; float f; } c{(unsigned)(unsigned short)b << 16};
    return c.f;
}

__global__ void vq_prep(const float* __restrict__ E,
                        float* __restrict__ ET,
                        float* __restrict__ ckseq,
                        char* __restrict__ EB) {
    #pragma clang fp contract(off)
    int n = blockIdx.x * blockDim.x + threadIdx.x;  // codebook col 0..1023
    if (n >= KCB) return;
    float col[DIM];
    float c = 0.f;
    #pragma unroll
    for (int d = 0; d < DIM; ++d) {
        float v = E[d * KCB + n];      // coalesced along n
        col[d] = v;
        ET[n * DIM + d] = v;
        float q = v * v;
        c = c + q;                     // sequential (numpy axis-0 reduce)
    }
    ckseq[n] = c;
    // EB layout: tile t = n>>4 (16 cols), col-in-tile l15 = n&15.
    // Part p: 0 = hi d0-31, 1 = hi d32-63 (HI ONLY; 2-product scheme).
    // Lane l = g*16+l15 holds d = p*32 + g*8 + j, j=0..7, 16 B per lane
    // at EB + t*2048 + p*1024 + l*16.  (-2e is an exact scale.)
    int t = n >> 4, l15 = n & 15;
    char* base = EB + t * 2048;
    #pragma unroll
    for (int p = 0; p < 2; ++p) {
        #pragma unroll
        for (int g = 0; g < 4; ++g) {
            s16x8 w;
            #pragma unroll
            for (int j = 0; j < 8; ++j)
                w[j] = bfb(-2.f * col[p * 32 + g * 8 + j]);
            *(s16x8*)(base + p * 1024 + (g * 16 + l15) * 16) = w;
        }
    }
}

__global__ __launch_bounds__(256, 4)
__attribute__((amdgpu_waves_per_eu(4, 4)))
void vq_mfma(const float* __restrict__ x, const float* __restrict__ ck,
             const char* __restrict__ EB, const float* __restrict__ ET,
             float* __restrict__ out, int* __restrict__ count,
             int* __restrict__ list, int list_cap) {
    __shared__ float ckls[KCB + 80];     // +80: pad reads at t=60..63 prefetch
    __shared__ int idxbuf[128];

    const int tid  = threadIdx.x;
    const int lane = tid & 63;
    const int wv   = tid >> 6;            // wave 0..3
    const int l15  = lane & 15;
    const int g    = lane >> 4;           // 0..3
    const int rowbase = blockIdx.x * 128; // 128 rows per block, 32 per wave

    // ---- stage ck LUT once (only block barrier in the kernel body) ----
    GLDS16(ck + wv * 256 + lane * 4, &ckls[wv * 256]);

    // ---- A fragments hi/lo: 2 rowtiles x 2 dblocks (32 VGPR persistent) ----
    s16x8 aH[2][2], aL[2][2];
    #pragma unroll
    for (int rt = 0; rt < 2; ++rt) {
        int row = rowbase + wv * 32 + rt * 16 + l15;
        const float* xp = x + (size_t)row * DIM + g * 8;
        #pragma unroll
        for (int s = 0; s < 2; ++s) {
            float val[8];
            float4 u = *(const float4*)(xp + s * 32);
            float4 v = *(const float4*)(xp + s * 32 + 4);
            val[0] = u.x; val[1] = u.y; val[2] = u.z; val[3] = u.w;
            val[4] = v.x; val[5] = v.y; val[6] = v.z; val[7] = v.w;
            s16x8 h, l;
            #pragma unroll
            for (int j = 0; j < 8; ++j) {
                short hb = bfb(val[j]);
                h[j] = hb;
                l[j] = bfb(val[j] - bf2f(hb));   // (xh+xl) ~ 17-bit accurate
            }
            aH[rt][s] = h;
            aL[rt][s] = l;
        }
    }
    __syncthreads();                      // ckls ready; no more block syncs

    // ---- top-2 state: slot = rt*4 + r -> row rt*16 + g*4 + r ----
    float tb1[8], tb2[8];
    int   tix[8];
    #pragma unroll
    for (int sl = 0; sl < 8; ++sl) { tb1[sl] = 1e30f; tb2[sl] = 1e30f; tix[sl] = 0; }

    // ---- barrier-free K-loop: distance-4 rolling register prefetch ----
    const char* ebp = EB + lane * 16;     // per-lane base
    s16x8 h0[4], h1[4];
    float ckv[4];
    #pragma unroll
    for (int i = 0; i < 4; ++i) {         // prologue: tiles 0..3 in flight
        h0[i]  = *(const s16x8*)(ebp + (size_t)i * 2048);
        h1[i]  = *(const s16x8*)(ebp + (size_t)i * 2048 + 1024);
        ckv[i] = ckls[i * 16 + l15];
    }

    #pragma unroll 1
    for (int t = 0; t < 64; t += 4) {
        #pragma unroll
        for (int i = 0; i < 4; ++i) {
            // ---- compute tile t+i from slot i ----
            {
                float cck = ckv[i];
                f32x4 cin = {cck, cck, cck, cck};
                int kc = (t + i) * 16 + l15;
                #pragma unroll
                for (int rt = 0; rt < 2; ++rt) {
                    f32x4 acc = cin;      // C-in = ||e||^2
                    acc = __builtin_amdgcn_mfma_f32_16x16x32_bf16(aH[rt][0], h0[i], acc, 0, 0, 0);
                    acc = __builtin_amdgcn_mfma_f32_16x16x32_bf16(aH[rt][1], h1[i], acc, 0, 0, 0);
                    acc = __builtin_amdgcn_mfma_f32_16x16x32_bf16(aL[rt][0], h0[i], acc, 0, 0, 0);
                    acc = __builtin_amdgcn_mfma_f32_16x16x32_bf16(aL[rt][1], h1[i], acc, 0, 0, 0);
                    #pragma unroll
                    for (int rr = 0; rr < 4; ++rr) {
                        float s = acc[rr];         // = ck - 2*dot
                        int sl = rt * 4 + rr;
                        bool cond = s < tb1[sl];
                        tb2[sl] = __builtin_amdgcn_fmed3f(s, tb1[sl], tb2[sl]);
                        tb1[sl] = fminf(tb1[sl], s);
                        tix[sl] = cond ? kc : tix[sl];
                    }
                }
            }
            // ---- reload slot i with tile t+4+i (t=60: pad tiles, unused) ----
            const char* p = ebp + (size_t)(t + 4 + i) * 2048;
            h0[i]  = *(const s16x8*)(p);
            h1[i]  = *(const s16x8*)(p + 1024);
            ckv[i] = ckls[(t + 4 + i) * 16 + l15];
        }
    }

    // ---- merge top-2 across the 16 lanes of each g-group ----
    #pragma unroll
    for (int m = 1; m <= 8; m <<= 1) {
        #pragma unroll
        for (int sl = 0; sl < 8; ++sl) {
            float ob1 = __shfl_xor(tb1[sl], m);
            float ob2 = __shfl_xor(tb2[sl], m);
            int   oid = __shfl_xor(tix[sl], m);
            if (ob1 < tb1[sl] || (ob1 == tb1[sl] && oid < tix[sl])) {
                tb2[sl] = fminf(tb1[sl], ob2);
                tb1[sl] = ob1;
                tix[sl] = oid;
            } else {
                tb2[sl] = fminf(tb2[sl], ob1);
            }
        }
    }

    if (l15 == 0) {
        #pragma unroll
        for (int sl = 0; sl < 8; ++sl) {
            int rloc = wv * 32 + (sl >> 2) * 16 + g * 4 + (sl & 3);
            idxbuf[rloc] = tix[sl];
            if (tb2[sl] - tb1[sl] < MARGIN) {
                int slot = atomicAdd(count, 1);
                if (slot < list_cap) list[slot] = rowbase + rloc;
            }
        }
    }
    __syncthreads();

    // ---- fused gather: out[rowbase + r][:] = ET[idx[r]][:] ----
    const float4* ET4 = (const float4*)ET;
    float4* out4 = (float4*)(out + (size_t)rowbase * DIM);
    #pragma unroll
    for (int p = 0; p < 8; ++p) {
        int f = p * 256 + tid;           // 0..2047
        int r = f >> 4, dq = f & 15;
        out4[f] = ET4[idxbuf[r] * 16 + dq];
    }
}

// Exact numpy-f32-chain argmin for flagged rows (semantics validated R2-R10).
// One wave per row; lane handles 16 k's (k = c*64 + lane, coalesced E[d][k]
// loads, 2 chains interleaved). Packed-key (ordbits(dist)<<32)|k lex-min
// gives exact first-index tie-break. Gathers + rewrites the row directly.
__global__ __launch_bounds__(256)
void vq_refine2(const float* __restrict__ x, const float* __restrict__ E,
                const float* __restrict__ ckseq, const float* __restrict__ ET,
                float* __restrict__ out,
                const int* __restrict__ count, const int* __restrict__ list,
                int list_cap) {
    #pragma clang fp contract(off)
    int n = *count;
    if (n > list_cap) n = list_cap;
    int gw = (blockIdx.x * blockDim.x + threadIdx.x) >> 6;
    int lane = threadIdx.x & 63;
    int nw = (gridDim.x * blockDim.x) >> 6;
    for (int slot = gw; slot < n; slot += nw) {
        int row = list[slot];
        const f32x4* z4 = (const f32x4*)(x + (size_t)row * DIM);

        // ||z||^2: numpy pairwise_sum n=64 (8-acc unrolled), validated order
        float r8[8];
        {
            f32x4 a = z4[0], b = z4[1];
            r8[0] = a.x * a.x; r8[1] = a.y * a.y; r8[2] = a.z * a.z; r8[3] = a.w * a.w;
            r8[4] = b.x * b.x; r8[5] = b.y * b.y; r8[6] = b.z * b.z; r8[7] = b.w * b.w;
        }
        #pragma unroll
        for (int gi = 1; gi < 8; ++gi) {
            f32x4 a = z4[gi * 2], b = z4[gi * 2 + 1];
            r8[0] = r8[0] + a.x * a.x; r8[1] = r8[1] + a.y * a.y;
            r8[2] = r8[2] + a.z * a.z; r8[3] = r8[3] + a.w * a.w;
            r8[4] = r8[4] + b.x * b.x; r8[5] = r8[5] + b.y * b.y;
            r8[6] = r8[6] + b.z * b.z; r8[7] = r8[7] + b.w * b.w;
        }
        float A = ((r8[0] + r8[1]) + (r8[2] + r8[3]))
                + ((r8[4] + r8[5]) + (r8[6] + r8[7]));

        unsigned long long key = ~0ull;
        for (int c = 0; c < 16; c += 2) {     // 2 chains interleaved
            int k0 = c * 64 + lane, k1 = k0 + 64;
            float s0 = 0.f, s1 = 0.f;
            #pragma unroll
            for (int q = 0; q < 16; ++q) {    // sequential fmaf over d (BLAS emu)
                f32x4 zv = z4[q];
                s0 = fmaf(zv.x, E[(4 * q + 0) * KCB + k0], s0);
                s1 = fmaf(zv.x, E[(4 * q + 0) * KCB + k1], s1);
                s0 = fmaf(zv.y, E[(4 * q + 1) * KCB + k0], s0);
                s1 = fmaf(zv.y, E[(4 * q + 1) * KCB + k1], s1);
                s0 = fmaf(zv.z, E[(4 * q + 2) * KCB + k0], s0);
                s1 = fmaf(zv.z, E[(4 * q + 2) * KCB + k1], s1);
                s0 = fmaf(zv.w, E[(4 * q + 3) * KCB + k0], s0);
                s1 = fmaf(zv.w, E[(4 * q + 3) * KCB + k1], s1);
            }
            float d0 = (A + ckseq[k0]) - 2.0f * s0;
            float d1 = (A + ckseq[k1]) - 2.0f * s1;
            unsigned u0 = __float_as_uint(d0);
            unsigned o0 = u0 ^ ((u0 & 0x80000000u) ? 0xFFFFFFFFu : 0x80000000u);
            unsigned u1 = __float_as_uint(d1);
            unsigned o1 = u1 ^ ((u1 & 0x80000000u) ? 0xFFFFFFFFu : 0x80000000u);
            unsigned long long key0 = ((unsigned long long)o0 << 32) | (unsigned)k0;
            unsigned long long key1 = ((unsigned long long)o1 << 32) | (unsigned)k1;
            key = key0 < key ? key0 : key;
            key = key1 < key ? key1 : key;
        }
        #pragma unroll
        for (int off = 32; off; off >>= 1) {
            unsigned long long ok = __shfl_xor(key, off);
            key = ok < key ? ok : key;
        }
        unsigned bk = (unsigned)(key & 0xFFFFFFFFu);
        out[(size_t)row * DIM + lane] = ET[(size_t)bk * DIM + lane];
    }
}

extern "C" void kernel_launch(void* const* d_in, const int* in_sizes, int n_in,
                              void* d_out, int out_size, void* d_ws, size_t ws_size,
                              hipStream_t stream) {
    const float* x = (const float*)d_in[0];
    const float* E = (const float*)d_in[1];
    float* out = (float*)d_out;

    char* ws = (char*)d_ws;
    float* ET  = (float*)(ws + ET_OFF);
    float* ck  = (float*)(ws + CK_OFF);
    char*  EB  = ws + EB_OFF;
    int*   cnt = (int*)(ws + CNT_OFF);
    int*   lst = (int*)(ws + LIST_OFF);
    long long avail = (long long)ws_size - LIST_OFF;
    int list_cap = avail > 0 ? (int)(avail / 4) : 0;
    if (list_cap > LIST_CAP) list_cap = LIST_CAP;

    hipMemsetAsync(cnt, 0, sizeof(int), stream);
    vq_prep<<<4, 256, 0, stream>>>(E, ET, ck, EB);
    vq_mfma<<<NROWS / 128, 256, 0, stream>>>(x, ck, EB, ET, out, cnt, lst, list_cap);
    vq_refine2<<<1024, 256, 0, stream>>>(x, E, ck, ET, out, cnt, lst, list_cap);
}

// Round 12
// 206.206 us; speedup vs baseline: 1.0404x; 1.0404x over previous
//
#include <hip/hip_runtime.h>
#include <hip/hip_bf16.h>

// VectorQuantiser: x [32,64,64,64] f32, embeddings [64,1024] f32.
// argmin_k ||z - e_k||^2 over K=1024 for N=131072 rows of D=64; out = codewords.
//
//  k0 vq_prep:   ET[k][d] f32; ckseq[k] = sequential f32 sum e^2 (numpy order);
//                EB = bf16 HI-ONLY fragments of (-2e), lane-linear, 64 tiles
//                of 2048 B (+2 pad tiles) for per-wave register streaming.
//  k1 vq_mfma:   1-WAVE BLOCKS (64 thr), 32 rows/wave, grid 4096 -> 16 waves/CU
//                of work (R11 pm: 1024-block grids were occupancy-capped at 4
//                blk/CU; all stalls uncovered). score = ck - 2*dot via
//                2-product MFMA (xh+xl)*eh, 4-deep C-chain; distance-2 rolling
//                register prefetch with NAMED slots (R10 codegen pattern).
//                MARGIN 8e-3 = 8.8 sigma of score err (validated R11).
//  k2 vq_refine2: wave per flagged row (~7k): exact numpy-f32 chain over all
//                1024 k (coalesced E[d][k] loads), packed-key argmin, direct
//                rewrite. Semantics validated R2-R11.

#define NROWS (32 * 64 * 64)   // 131072
#define DIM   64
#define KCB   1024
#define MARGIN 8e-3f

// ws layout (bytes):
#define ET_OFF    0           // float[1024*64] = 262144
#define CK_OFF    262144      // float[1088] pad -> 4352
#define EB_OFF    266496      // 66 tiles * 2048 B = 135168 (64 + 2 prefetch pad)
#define CNT_OFF   401664      // int (+pad)
#define LIST_OFF  401920      // int[cap]
#define LIST_CAP  12288

typedef float  f32x4 __attribute__((ext_vector_type(4)));
typedef short  s16x8 __attribute__((ext_vector_type(8)));

#define GLDS16(g, l) __builtin_amdgcn_global_load_lds( \
    (const __attribute__((address_space(1))) unsigned int*)(g), \
    (__attribute__((address_space(3))) unsigned int*)(l), 16, 0, 0)

static __device__ inline short bfb(float f) {   // f32 -> bf16 bits, RNE
    union { float f; unsigned u; } c{f};
    unsigned r = c.u + 0x7fffu + ((c.u >> 16) & 1u);
    return (short)(r >> 16);
}
static __device__ inline float bf2f(short b) {  // bf16 bits -> f32
    union { unsigned u; float f; } c{(unsigned)(unsigned short)b << 16};
    return c.f;
}

__global__ void vq_prep(const float* __restrict__ E,
                        float* __restrict__ ET,
                        float* __restrict__ ckseq,
                        char* __restrict__ EB) {
    #pragma clang fp contract(off)
    int n = blockIdx.x * blockDim.x + threadIdx.x;  // codebook col 0..1023
    if (n >= KCB) return;
    float col[DIM];
    float c = 0.f;
    #pragma unroll
    for (int d = 0; d < DIM; ++d) {
        float v = E[d * KCB + n];      // coalesced along n
        col[d] = v;
        ET[n * DIM + d] = v;
        float q = v * v;
        c = c + q;                     // sequential (numpy axis-0 reduce)
    }
    ckseq[n] = c;
    // EB layout: tile t = n>>4 (16 cols), col-in-tile l15 = n&15.
    // Part p: 0 = hi d0-31, 1 = hi d32-63 (HI ONLY; 2-product scheme).
    // Lane l = g*16+l15 holds d = p*32 + g*8 + j, j=0..7, 16 B per lane
    // at EB + t*2048 + p*1024 + l*16.  (-2e is an exact scale.)
    int t = n >> 4, l15 = n & 15;
    char* base = EB + t * 2048;
    #pragma unroll
    for (int p = 0; p < 2; ++p) {
        #pragma unroll
        for (int g = 0; g < 4; ++g) {
            s16x8 w;
            #pragma unroll
            for (int j = 0; j < 8; ++j)
                w[j] = bfb(-2.f * col[p * 32 + g * 8 + j]);
            *(s16x8*)(base + p * 1024 + (g * 16 + l15) * 16) = w;
        }
    }
}

__global__ __launch_bounds__(64)
__attribute__((amdgpu_waves_per_eu(4, 8)))
void vq_mfma(const float* __restrict__ x, const float* __restrict__ ck,
             const char* __restrict__ EB, const float* __restrict__ ET,
             float* __restrict__ out, int* __restrict__ count,
             int* __restrict__ list, int list_cap) {
    __shared__ float ckls[1088];         // 1024 + pad (prefetch reads t<=65)
    __shared__ int idxbuf[32];

    const int lane = threadIdx.x & 63;
    const int l15  = lane & 15;
    const int g    = lane >> 4;           // 0..3
    const int rowbase = blockIdx.x * 32;  // 32 rows per 1-wave block

    // ---- stage ck LUT (4 KB) via global_load_lds, in flight during A-conv --
    #pragma unroll
    for (int i = 0; i < 4; ++i)
        GLDS16(ck + i * 256 + lane * 4, &ckls[i * 256]);

    // ---- A fragments hi/lo: 2 rowtiles x 2 dblocks (32 VGPR persistent) ----
    s16x8 aH[2][2], aL[2][2];
    #pragma unroll
    for (int rt = 0; rt < 2; ++rt) {
        int row = rowbase + rt * 16 + l15;
        const float* xp = x + (size_t)row * DIM + g * 8;
        #pragma unroll
        for (int s = 0; s < 2; ++s) {
            float val[8];
            float4 u = *(const float4*)(xp + s * 32);
            float4 v = *(const float4*)(xp + s * 32 + 4);
            val[0] = u.x; val[1] = u.y; val[2] = u.z; val[3] = u.w;
            val[4] = v.x; val[5] = v.y; val[6] = v.z; val[7] = v.w;
            s16x8 h, l;
            #pragma unroll
            for (int j = 0; j < 8; ++j) {
                short hb = bfb(val[j]);
                h[j] = hb;
                l[j] = bfb(val[j] - bf2f(hb));   // (xh+xl) ~17-bit accurate
            }
            aH[rt][s] = h;
            aL[rt][s] = l;
        }
    }
    __syncthreads();                      // ckls resident (1-wave: cheap)

    // ---- top-2 state: slot = rt*4 + rr -> row rt*16 + g*4 + rr ----
    float tb1[8], tb2[8];
    int   tix[8];
    #pragma unroll
    for (int sl = 0; sl < 8; ++sl) { tb1[sl] = 1e30f; tb2[sl] = 1e30f; tix[sl] = 0; }

    auto compute = [&](int kc, s16x8 bh0, s16x8 bh1, float cck) {
        f32x4 cin = {cck, cck, cck, cck};
        #pragma unroll
        for (int rt = 0; rt < 2; ++rt) {
            f32x4 acc = cin;              // C-in = ||e||^2
            acc = __builtin_amdgcn_mfma_f32_16x16x32_bf16(aH[rt][0], bh0, acc, 0, 0, 0);
            acc = __builtin_amdgcn_mfma_f32_16x16x32_bf16(aH[rt][1], bh1, acc, 0, 0, 0);
            acc = __builtin_amdgcn_mfma_f32_16x16x32_bf16(aL[rt][0], bh0, acc, 0, 0, 0);
            acc = __builtin_amdgcn_mfma_f32_16x16x32_bf16(aL[rt][1], bh1, acc, 0, 0, 0);
            #pragma unroll
            for (int rr = 0; rr < 4; ++rr) {
                float s = acc[rr];        // = ck - 2*dot
                int sl = rt * 4 + rr;
                bool cond = s < tb1[sl];
                tb2[sl] = __builtin_amdgcn_fmed3f(s, tb1[sl], tb2[sl]);
                tb1[sl] = fminf(tb1[sl], s);
                tix[sl] = cond ? kc : tix[sl];
            }
        }
    };

    // ---- barrier-free K-loop: distance-2 rolling prefetch, NAMED slots ----
    const char* ebp = EB + lane * 16;     // per-lane base
    s16x8 s0h0 = *(const s16x8*)(ebp);
    s16x8 s0h1 = *(const s16x8*)(ebp + 1024);
    s16x8 s1h0 = *(const s16x8*)(ebp + 2048);
    s16x8 s1h1 = *(const s16x8*)(ebp + 3072);
    float ck0 = ckls[l15];
    float ck1 = ckls[16 + l15];

    #pragma unroll 1
    for (int t = 0; t < 64; t += 2) {
        compute(t * 16 + l15, s0h0, s0h1, ck0);
        {   // reload slot0 <- tile t+2 (t=62 reads pad tile; values unused)
            const char* q = ebp + (size_t)(t + 2) * 2048;
            s0h0 = *(const s16x8*)(q);
            s0h1 = *(const s16x8*)(q + 1024);
            ck0  = ckls[(t + 2) * 16 + l15];
        }
        compute((t + 1) * 16 + l15, s1h0, s1h1, ck1);
        {   // reload slot1 <- tile t+3
            const char* q = ebp + (size_t)(t + 3) * 2048;
            s1h0 = *(const s16x8*)(q);
            s1h1 = *(const s16x8*)(q + 1024);
            ck1  = ckls[(t + 3) * 16 + l15];
        }
    }

    // ---- merge top-2 across the 16 lanes of each g-group ----
    #pragma unroll
    for (int m = 1; m <= 8; m <<= 1) {
        #pragma unroll
        for (int sl = 0; sl < 8; ++sl) {
            float ob1 = __shfl_xor(tb1[sl], m);
            float ob2 = __shfl_xor(tb2[sl], m);
            int   oid = __shfl_xor(tix[sl], m);
            if (ob1 < tb1[sl] || (ob1 == tb1[sl] && oid < tix[sl])) {
                tb2[sl] = fminf(tb1[sl], ob2);
                tb1[sl] = ob1;
                tix[sl] = oid;
            } else {
                tb2[sl] = fminf(tb2[sl], ob1);
            }
        }
    }

    if (l15 == 0) {
        #pragma unroll
        for (int sl = 0; sl < 8; ++sl) {
            int rloc = (sl >> 2) * 16 + g * 4 + (sl & 3);
            idxbuf[rloc] = tix[sl];
            if (tb2[sl] - tb1[sl] < MARGIN) {
                int slot = atomicAdd(count, 1);
                if (slot < list_cap) list[slot] = rowbase + rloc;
            }
        }
    }
    __syncthreads();

    // ---- fused gather: out[rowbase + r][:] = ET[idx[r]][:] ----
    const float4* ET4 = (const float4*)ET;
    float4* out4 = (float4*)(out + (size_t)rowbase * DIM);
    #pragma unroll
    for (int p = 0; p < 8; ++p) {
        int f = p * 64 + lane;           // 0..511 = 32 rows x 16 float4
        int r = f >> 4, dq = f & 15;
        out4[f] = ET4[idxbuf[r] * 16 + dq];
    }
}

// Exact numpy-f32-chain argmin for flagged rows (semantics validated R2-R11).
// One wave per row; lane handles 16 k's (k = c*64 + lane, coalesced E[d][k]
// loads, 2 chains interleaved). Packed-key (ordbits(dist)<<32)|k lex-min
// gives exact first-index tie-break. Gathers + rewrites the row directly.
__global__ __launch_bounds__(256)
void vq_refine2(const float* __restrict__ x, const float* __restrict__ E,
                const float* __restrict__ ckseq, const float* __restrict__ ET,
                float* __restrict__ out,
                const int* __restrict__ count, const int* __restrict__ list,
                int list_cap) {
    #pragma clang fp contract(off)
    int n = *count;
    if (n > list_cap) n = list_cap;
    int gw = (blockIdx.x * blockDim.x + threadIdx.x) >> 6;
    int lane = threadIdx.x & 63;
    int nw = (gridDim.x * blockDim.x) >> 6;
    for (int slot = gw; slot < n; slot += nw) {
        int row = list[slot];
        const f32x4* z4 = (const f32x4*)(x + (size_t)row * DIM);

        // ||z||^2: numpy pairwise_sum n=64 (8-acc unrolled), validated order
        float r8[8];
        {
            f32x4 a = z4[0], b = z4[1];
            r8[0] = a.x * a.x; r8[1] = a.y * a.y; r8[2] = a.z * a.z; r8[3] = a.w * a.w;
            r8[4] = b.x * b.x; r8[5] = b.y * b.y; r8[6] = b.z * b.z; r8[7] = b.w * b.w;
        }
        #pragma unroll
        for (int gi = 1; gi < 8; ++gi) {
            f32x4 a = z4[gi * 2], b = z4[gi * 2 + 1];
            r8[0] = r8[0] + a.x * a.x; r8[1] = r8[1] + a.y * a.y;
            r8[2] = r8[2] + a.z * a.z; r8[3] = r8[3] + a.w * a.w;
            r8[4] = r8[4] + b.x * b.x; r8[5] = r8[5] + b.y * b.y;
            r8[6] = r8[6] + b.z * b.z; r8[7] = r8[7] + b.w * b.w;
        }
        float A = ((r8[0] + r8[1]) + (r8[2] + r8[3]))
                + ((r8[4] + r8[5]) + (r8[6] + r8[7]));

        unsigned long long key = ~0ull;
        for (int c = 0; c < 16; c += 2) {     // 2 chains interleaved
            int k0 = c * 64 + lane, k1 = k0 + 64;
            float s0 = 0.f, s1 = 0.f;
            #pragma unroll
            for (int q = 0; q < 16; ++q) {    // sequential fmaf over d (BLAS emu)
                f32x4 zv = z4[q];
                s0 = fmaf(zv.x, E[(4 * q + 0) * KCB + k0], s0);
                s1 = fmaf(zv.x, E[(4 * q + 0) * KCB + k1], s1);
                s0 = fmaf(zv.y, E[(4 * q + 1) * KCB + k0], s0);
                s1 = fmaf(zv.y, E[(4 * q + 1) * KCB + k1], s1);
                s0 = fmaf(zv.z, E[(4 * q + 2) * KCB + k0], s0);
                s1 = fmaf(zv.z, E[(4 * q + 2) * KCB + k1], s1);
                s0 = fmaf(zv.w, E[(4 * q + 3) * KCB + k0], s0);
                s1 = fmaf(zv.w, E[(4 * q + 3) * KCB + k1], s1);
            }
            float d0 = (A + ckseq[k0]) - 2.0f * s0;
            float d1 = (A + ckseq[k1]) - 2.0f * s1;
            unsigned u0 = __float_as_uint(d0);
            unsigned o0 = u0 ^ ((u0 & 0x80000000u) ? 0xFFFFFFFFu : 0x80000000u);
            unsigned u1 = __float_as_uint(d1);
            unsigned o1 = u1 ^ ((u1 & 0x80000000u) ? 0xFFFFFFFFu : 0x80000000u);
            unsigned long long key0 = ((unsigned long long)o0 << 32) | (unsigned)k0;
            unsigned long long key1 = ((unsigned long long)o1 << 32) | (unsigned)k1;
            key = key0 < key ? key0 : key;
            key = key1 < key ? key1 : key;
        }
        #pragma unroll
        for (int off = 32; off; off >>= 1) {
            unsigned long long ok = __shfl_xor(key, off);
            key = ok < key ? ok : key;
        }
        unsigned bk = (unsigned)(key & 0xFFFFFFFFu);
        out[(size_t)row * DIM + lane] = ET[(size_t)bk * DIM + lane];
    }
}

extern "C" void kernel_launch(void* const* d_in, const int* in_sizes, int n_in,
                              void* d_out, int out_size, void* d_ws, size_t ws_size,
                              hipStream_t stream) {
    const float* x = (const float*)d_in[0];
    const float* E = (const float*)d_in[1];
    float* out = (float*)d_out;

    char* ws = (char*)d_ws;
    float* ET  = (float*)(ws + ET_OFF);
    float* ck  = (float*)(ws + CK_OFF);
    char*  EB  = ws + EB_OFF;
    int*   cnt = (int*)(ws + CNT_OFF);
    int*   lst = (int*)(ws + LIST_OFF);
    long long avail = (long long)ws_size - LIST_OFF;
    int list_cap = avail > 0 ? (int)(avail / 4) : 0;
    if (list_cap > LIST_CAP) list_cap = LIST_CAP;

    hipMemsetAsync(cnt, 0, sizeof(int), stream);
    vq_prep<<<4, 256, 0, stream>>>(E, ET, ck, EB);
    vq_mfma<<<NROWS / 32, 64, 0, stream>>>(x, ck, EB, ET, out, cnt, lst, list_cap);
    vq_refine2<<<1024, 256, 0, stream>>>(x, E, ck, ET, out, cnt, lst, list_cap);
}